// Round 4
// baseline (683.125 us; speedup 1.0000x reference)
//
#include <hip/hip_runtime.h>

typedef unsigned short u16;
typedef __attribute__((ext_vector_type(8))) short bf16x8;
typedef __attribute__((ext_vector_type(4))) float f32x4;

__device__ __forceinline__ u16 f2b(float f) {
  union { float f; unsigned u; } c; c.f = f;
  unsigned u = c.u + 0x7fffu + ((c.u >> 16) & 1u);
  return (u16)(u >> 16);
}
__device__ __forceinline__ float b2f(u16 h) {
  union { unsigned u; float f; } c; c.u = ((unsigned)h) << 16;
  return c.f;
}
__device__ __forceinline__ void g2lds16(const void* g, void* l) {
  __builtin_amdgcn_global_load_lds((const __attribute__((address_space(1))) void*)g,
                                   (__attribute__((address_space(3))) void*)l, 16, 0, 0);
}

// ---------------------------------------------------------------- f32 -> bf16
__global__ __launch_bounds__(256) void cvtk(const float* __restrict__ in,
                                            u16* __restrict__ out, int n4) {
  int i = blockIdx.x * 256 + threadIdx.x;
  if (i < n4) {
    float4 f = ((const float4*)in)[i];
    ushort4 o;
    o.x = f2b(f.x); o.y = f2b(f.y); o.z = f2b(f.z); o.w = f2b(f.w);
    ((ushort4*)out)[i] = o;
  }
}

// ---------------------------------------------------------------- big GEMM, 8-phase-style
// outb[m,n] = bf16( sum_k A[m,k]*B[n,k] + bias[n] ),  K=768 fixed.
// 256x256 tile, BK=32, 8 waves (2Mx4N), 4-deep LDS rotation (128 KiB):
// compute K-tile t from buf[t&3], stage tile t+3 (3-tile prefetch lead).
// Per group (K-tile): 2 phases x {ds_read || g2lds -> barrier -> lgkmcnt(0)
// -> setprio(1) -> 16 MFMA -> setprio(0) -> barrier}.
// Wait ledger: 4 loads/thread/group; group-end vmcnt(8) leaves groups {t-1,t}
// in flight => tile t+1 (staged group t-2) landed before group t+1 reads it.
// Drain: vmcnt(4) at t=nkt-3, vmcnt(0) at t=nkt-2.
// LDS swizzle: 64B rows, phys 16B part p of row r holds logical p^((r>>1)&3);
// read-side XOR folds to per-thread constant; 2-way banks only (free).
__global__ __launch_bounds__(512, 2)
void gemm8(const u16* __restrict__ Aa, const u16* __restrict__ Bw,
           const float* __restrict__ bias, u16* __restrict__ outb,
           int N, int NT, int nwg)
{
  __shared__ __align__(16) u16 As[4][256 * 32];
  __shared__ __align__(16) u16 Bs[4][256 * 32];
  constexpr int K = 768;
  constexpr int nkt = 24;            // K / 32
  const int tid = threadIdx.x;
  const int lane = tid & 63;
  const int wave = tid >> 6;
  const int r16 = lane & 15, rq = lane >> 4;
  const int wr = wave >> 2, wc = wave & 3;

  // bijective XCD swizzle (m204 form, any nwg)
  const int q8 = nwg >> 3, r8 = nwg & 7;
  const int xcd = blockIdx.x & 7, pos = blockIdx.x >> 3;
  const int wg = (xcd < r8 ? xcd * (q8 + 1) : r8 * (q8 + 1) + (xcd - r8) * q8) + pos;
  const long am0 = (long)(wg / NT) * 256;
  const long bn0 = (long)(wg % NT) * 256;

  // staging constants: thread covers chunks tid (rows 0-127) and tid+512 (rows 128-255)
  const int srow = tid >> 2;
  const int lpart = (tid & 3) ^ ((srow >> 1) & 3);
  const u16* aS = Aa + (am0 + srow) * (long)K + lpart * 8;
  const u16* bS = Bw + (bn0 + srow) * (long)K + lpart * 8;
  // frag-read physical part offset (u16 units) — constant per thread
  const int pp8 = (rq ^ ((r16 >> 1) & 3)) * 8;

  f32x4 acc[8][4];
  const f32x4 zero = {0.f, 0.f, 0.f, 0.f};
#pragma unroll
  for (int i = 0; i < 8; ++i)
#pragma unroll
    for (int j = 0; j < 4; ++j) acc[i][j] = zero;

  // prologue: stage tiles 0..2 into bufs 0..2
#pragma unroll
  for (int ts = 0; ts < 3; ++ts) {
    g2lds16(aS + ts * 32,           As[ts] + tid * 8);
    g2lds16(aS + ts * 32 + 128 * K, As[ts] + tid * 8 + 4096);
    g2lds16(bS + ts * 32,           Bs[ts] + tid * 8);
    g2lds16(bS + ts * 32 + 128 * K, Bs[ts] + tid * 8 + 4096);
  }
  asm volatile("s_waitcnt vmcnt(0)" ::: "memory");
  __builtin_amdgcn_sched_barrier(0);
  __builtin_amdgcn_s_barrier();
  __builtin_amdgcn_sched_barrier(0);

  for (int t = 0; t < nkt; ++t) {
    const u16* Ab = As[t & 3];
    const u16* Bb = Bs[t & 3];
    const bool st = (t < nkt - 3);
    bf16x8 a0[4], b0[4], a1[4];
    // ---- phase A: reads (i 0-3, all j) + stage A-chunks of tile t+3 ----
#pragma unroll
    for (int i = 0; i < 4; ++i)
      a0[i] = *(const bf16x8*)(Ab + (wr * 128 + i * 16 + r16) * 32 + pp8);
#pragma unroll
    for (int j = 0; j < 4; ++j)
      b0[j] = *(const bf16x8*)(Bb + (wc * 64 + j * 16 + r16) * 32 + pp8);
    if (st) {
      const u16* s = aS + (t + 3) * 32;
      u16* d = As[(t + 3) & 3] + tid * 8;
      g2lds16(s, d);
      g2lds16(s + 128 * K, d + 4096);
    }
    __builtin_amdgcn_sched_barrier(0);
    __builtin_amdgcn_s_barrier();
    __builtin_amdgcn_sched_barrier(0);
    asm volatile("s_waitcnt lgkmcnt(0)" ::: "memory");
    __builtin_amdgcn_sched_barrier(0);
    __builtin_amdgcn_s_setprio(1);
#pragma unroll
    for (int i = 0; i < 4; ++i)
#pragma unroll
      for (int j = 0; j < 4; ++j)
        acc[i][j] = __builtin_amdgcn_mfma_f32_16x16x32_bf16(a0[i], b0[j], acc[i][j], 0, 0, 0);
    __builtin_amdgcn_s_setprio(0);
    __builtin_amdgcn_sched_barrier(0);
    __builtin_amdgcn_s_barrier();
    __builtin_amdgcn_sched_barrier(0);
    // ---- phase B: reads (i 4-7) + stage B-chunks + group-end wait ----
#pragma unroll
    for (int i = 0; i < 4; ++i)
      a1[i] = *(const bf16x8*)(Ab + (wr * 128 + (i + 4) * 16 + r16) * 32 + pp8);
    if (st) {
      const u16* s = bS + (t + 3) * 32;
      u16* d = Bs[(t + 3) & 3] + tid * 8;
      g2lds16(s, d);
      g2lds16(s + 128 * K, d + 4096);
      asm volatile("s_waitcnt vmcnt(8)" ::: "memory");
    } else if (t == nkt - 3) {
      asm volatile("s_waitcnt vmcnt(4)" ::: "memory");
    } else if (t == nkt - 2) {
      asm volatile("s_waitcnt vmcnt(0)" ::: "memory");
    }
    __builtin_amdgcn_sched_barrier(0);
    __builtin_amdgcn_s_barrier();
    __builtin_amdgcn_sched_barrier(0);
    asm volatile("s_waitcnt lgkmcnt(0)" ::: "memory");
    __builtin_amdgcn_sched_barrier(0);
    __builtin_amdgcn_s_setprio(1);
#pragma unroll
    for (int i = 0; i < 4; ++i)
#pragma unroll
      for (int j = 0; j < 4; ++j)
        acc[i + 4][j] = __builtin_amdgcn_mfma_f32_16x16x32_bf16(a1[i], b0[j], acc[i + 4][j], 0, 0, 0);
    __builtin_amdgcn_s_setprio(0);
    __builtin_amdgcn_sched_barrier(0);
    __builtin_amdgcn_s_barrier();
    __builtin_amdgcn_sched_barrier(0);
  }

  // epilogue: D row=(lane>>4)*4+r, col=lane&15
#pragma unroll
  for (int j = 0; j < 4; ++j) {
    int col = (int)bn0 + wc * 64 + j * 16 + r16;
    float bb = bias[col];
#pragma unroll
    for (int i = 0; i < 8; ++i) {
      long row = am0 + wr * 128 + i * 16 + rq * 4;
#pragma unroll
      for (int r = 0; r < 4; ++r)
        outb[(row + r) * (long)N + col] = f2b(acc[i][j][r] + bb);
    }
  }
}

// ---------------------------------------------------------------- small GEMM (2-phase dbuf)
// MODE 1: store f32 to outf AND bf16 to outb
// MODE 2: outf[idx] += (acc+bias)*alpha[n]
template<int MODE>
__global__ __launch_bounds__(256)
void gemm_bt(const u16* __restrict__ Aa, const u16* __restrict__ Bw,
             const float* __restrict__ bias, const float* __restrict__ alpha,
             float* __restrict__ outf, u16* __restrict__ outb,
             int N, int K, int NT, int nwg)
{
  __shared__ u16 As[2][128 * 64];
  __shared__ u16 Bs[2][128 * 64];
  const int tid = threadIdx.x;
  const int wave = tid >> 6, lane = tid & 63;
  const int r16 = lane & 15, rq = lane >> 4;
  const int wr = wave >> 1, wc = wave & 1;

  const int q8 = nwg >> 3;
  const int wg = (blockIdx.x & 7) * q8 + (blockIdx.x >> 3);
  const long am0 = (long)(wg / NT) * 128;
  const long bn0 = (long)(wg % NT) * 128;

  f32x4 acc[4][4];
  const f32x4 zero = {0.f, 0.f, 0.f, 0.f};
#pragma unroll
  for (int i = 0; i < 4; ++i)
#pragma unroll
    for (int j = 0; j < 4; ++j) acc[i][j] = zero;

  auto stage = [&](int kt, int buf) {
#pragma unroll
    for (int i = 0; i < 4; ++i) {
      int c = i * 256 + tid;
      int row = c >> 3;
      int lp = (c & 7) ^ (row & 7);
      g2lds16(Aa + (am0 + row) * (long)K + kt * 64 + lp * 8,
              As[buf] + (i * 256 + wave * 64) * 8);
      g2lds16(Bw + (bn0 + row) * (long)K + kt * 64 + lp * 8,
              Bs[buf] + (i * 256 + wave * 64) * 8);
    }
  };

  const int nkt = K >> 6;
  stage(0, 0);
  for (int kt = 0; kt < nkt; ++kt) {
    const int cur = kt & 1;
    if (kt + 1 < nkt) {
      stage(kt + 1, cur ^ 1);
      asm volatile("s_waitcnt vmcnt(8)" ::: "memory");
    } else {
      asm volatile("s_waitcnt vmcnt(0)" ::: "memory");
    }
    __builtin_amdgcn_sched_barrier(0);
    __builtin_amdgcn_s_barrier();
    __builtin_amdgcn_sched_barrier(0);
#pragma unroll
    for (int kk = 0; kk < 2; ++kk) {
      bf16x8 af[4], bfr[4];
#pragma unroll
      for (int i = 0; i < 4; ++i) {
        int ra = wr * 64 + i * 16 + r16;
        af[i] = *(const bf16x8*)(As[cur] + ((ra * 128 + ((kk * 64 + rq * 16) ^ ((ra & 7) << 4))) >> 1));
        int rb = wc * 64 + i * 16 + r16;
        bfr[i] = *(const bf16x8*)(Bs[cur] + ((rb * 128 + ((kk * 64 + rq * 16) ^ ((rb & 7) << 4))) >> 1));
      }
#pragma unroll
      for (int i = 0; i < 4; ++i)
#pragma unroll
        for (int j = 0; j < 4; ++j)
          acc[i][j] = __builtin_amdgcn_mfma_f32_16x16x32_bf16(af[i], bfr[j], acc[i][j], 0, 0, 0);
    }
    __builtin_amdgcn_sched_barrier(0);
    __builtin_amdgcn_s_barrier();
    __builtin_amdgcn_sched_barrier(0);
  }

#pragma unroll
  for (int j = 0; j < 4; ++j) {
    int col = (int)bn0 + wc * 64 + j * 16 + r16;
    float bb = bias[col];
#pragma unroll
    for (int i = 0; i < 4; ++i) {
      long row = am0 + wr * 64 + i * 16 + rq * 4;
#pragma unroll
      for (int r = 0; r < 4; ++r) {
        float v = acc[i][j][r] + bb;
        long idx = (row + r) * (long)N + col;
        if constexpr (MODE == 1) {
          outf[idx] = v;
          outb[idx] = f2b(v);
        } else {
          outf[idx] += v * alpha[col];
        }
      }
    }
  }
}

// ---------------------------------------------------------------- attention
// One workgroup per (group g, head h). qkv rows indexed via mode mapping:
//   MODE 0 (spatial): row = g*196 + s
//   MODE 1 (th): g=(b,w): row = b*3136 + w + (s/14)*196 + (s%14)*14
//   MODE 2 (tw): g=(b,h'): row = b*3136 + h'*14 + (s/14)*196 + (s%14)
// Output bf16; MODE 2 adds addin[idx] (th result) into its output.
template<int S, int MODE>
__global__ __launch_bounds__(256)
void attn_k(const u16* __restrict__ qkv, const u16* __restrict__ addin,
            u16* __restrict__ outp)
{
  constexpr int NT = (S + 15) / 16;   // 13 (S=196) or 14 (S=224)
  constexpr int NB = (NT + 1) / 2;    // 7
  __shared__ u16 Ks[224 * 64];
  __shared__ u16 Vt[64 * 224];
  __shared__ u16 Ps[4][512];

  const int g = blockIdx.x, h = blockIdx.y;
  const int tid = threadIdx.x;
  const int wave = tid >> 6, lane = tid & 63;
  const int r16 = lane & 15, rq = lane >> 4;

  int base;
  if constexpr (MODE == 0) base = g * 196;
  else if constexpr (MODE == 1) base = (g / 14) * 3136 + (g % 14);
  else base = (g / 14) * 3136 + (g % 14) * 14;

  auto rowof = [&](int s) -> long {
    if constexpr (MODE == 0) return base + s;
    int t = s / 14, u = s % 14;
    return base + t * 196 + u * (MODE == 1 ? 14 : 1);
  };

#pragma unroll
  for (int i = 0; i < 7; ++i) {
    int c = i * 256 + tid;
    int s = c >> 3, part = c & 7;
    int sc = (s < S) ? s : (S - 1);
    g2lds16(qkv + rowof(sc) * 2304 + 768 + h * 64 + ((part ^ (s & 7)) << 3),
            &Ks[(i * 256 + wave * 64) * 8]);
  }
#pragma unroll
  for (int i = 0; i < 7; ++i) {
    int c = i * 256 + tid;
    int s = c >> 3, part = c & 7;
    uint4 v; v.x = 0; v.y = 0; v.z = 0; v.w = 0;
    if (s < S) v = *(const uint4*)(qkv + rowof(s) * 2304 + 1536 + h * 64 + part * 8);
#pragma unroll
    for (int e = 0; e < 4; ++e) {
      unsigned w2 = (&v.x)[e];
      Vt[(part * 8 + 2 * e    ) * 224 + s] = (u16)(w2 & 0xffffu);
      Vt[(part * 8 + 2 * e + 1) * 224 + s] = (u16)(w2 >> 16);
    }
  }
  __syncthreads();

  for (int qt = wave; qt < NT; qt += 4) {
    int q0 = qt * 16;
    int qr = q0 + r16; if (qr > S - 1) qr = S - 1;
    const u16* gq = qkv + rowof(qr) * 2304 + h * 64 + rq * 8;
    bf16x8 aq0 = *(const bf16x8*)(gq);
    bf16x8 aq1 = *(const bf16x8*)(gq + 32);

    float p[4][NT];
#pragma unroll
    for (int kt = 0; kt < NT; ++kt) {
      f32x4 sc4 = {0.f, 0.f, 0.f, 0.f};
      int row = kt * 16 + r16;
      sc4 = __builtin_amdgcn_mfma_f32_16x16x32_bf16(
          aq0, *(const bf16x8*)(Ks + ((row * 128 + ((rq * 16) ^ ((row & 7) << 4))) >> 1)), sc4, 0, 0, 0);
      sc4 = __builtin_amdgcn_mfma_f32_16x16x32_bf16(
          aq1, *(const bf16x8*)(Ks + ((row * 128 + ((64 + rq * 16) ^ ((row & 7) << 4))) >> 1)), sc4, 0, 0, 0);
#pragma unroll
      for (int r = 0; r < 4; ++r) {
        float sv = sc4[r] * 0.125f;
        if (S == 196 && kt == NT - 1) {
          if (kt * 16 + r16 >= S) sv = -1e30f;
        }
        p[r][kt] = sv;
      }
    }

    float rcp[4];
#pragma unroll
    for (int r = 0; r < 4; ++r) {
      float m = p[r][0];
#pragma unroll
      for (int kt = 1; kt < NT; ++kt) m = fmaxf(m, p[r][kt]);
      m = fmaxf(m, __shfl_xor(m, 1));
      m = fmaxf(m, __shfl_xor(m, 2));
      m = fmaxf(m, __shfl_xor(m, 4));
      m = fmaxf(m, __shfl_xor(m, 8));
      float sum = 0.f;
#pragma unroll
      for (int kt = 0; kt < NT; ++kt) {
        float e = __expf(p[r][kt] - m);
        p[r][kt] = e; sum += e;
      }
      sum += __shfl_xor(sum, 1);
      sum += __shfl_xor(sum, 2);
      sum += __shfl_xor(sum, 4);
      sum += __shfl_xor(sum, 8);
      rcp[r] = 1.f / sum;
    }

    f32x4 oacc[4];
    const f32x4 zero = {0.f, 0.f, 0.f, 0.f};
#pragma unroll
    for (int nt = 0; nt < 4; ++nt) oacc[nt] = zero;
    u16* myP = Ps[wave];
#pragma unroll
    for (int jb = 0; jb < NB; ++jb) {
#pragma unroll
      for (int half = 0; half < 2; ++half) {
        int kt = jb * 2 + half;
#pragma unroll
        for (int r = 0; r < 4; ++r) {
          float pv = (kt < NT) ? p[r][kt] : 0.f;
          myP[(rq * 4 + r) * 32 + half * 16 + r16] = f2b(pv);
        }
      }
      asm volatile("s_waitcnt lgkmcnt(0)" ::: "memory");
      __builtin_amdgcn_sched_barrier(0);
      bf16x8 ap = *(const bf16x8*)(myP + r16 * 32 + rq * 8);
#pragma unroll
      for (int nt = 0; nt < 4; ++nt) {
        bf16x8 bv = *(const bf16x8*)(Vt + (nt * 16 + r16) * 224 + jb * 32 + rq * 8);
        oacc[nt] = __builtin_amdgcn_mfma_f32_16x16x32_bf16(ap, bv, oacc[nt], 0, 0, 0);
      }
      asm volatile("s_waitcnt lgkmcnt(0)" ::: "memory");
      __builtin_amdgcn_sched_barrier(0);
    }

#pragma unroll
    for (int r = 0; r < 4; ++r) {
      int q = q0 + rq * 4 + r;
      if (q < S) {
        long orow = rowof(q);
#pragma unroll
        for (int nt = 0; nt < 4; ++nt) {
          float v = oacc[nt][r] * rcp[r];
          long idx = orow * 768 + h * 64 + nt * 16 + r16;
          if constexpr (MODE == 2) v += b2f(addin[idx]);
          outp[idx] = f2b(v);
        }
      }
    }
  }
}

// ---------------------------------------------------------------- launch
extern "C" void kernel_launch(void* const* d_in, const int* in_sizes, int n_in,
                              void* d_out, int out_size, void* d_ws, size_t ws_size,
                              hipStream_t stream)
{
  const float* x       = (const float*)d_in[0];
  const float* W_in    = (const float*)d_in[1];
  const float* b_in    = (const float*)d_in[2];
  const float* W_out   = (const float*)d_in[3];
  const float* b_out   = (const float*)d_in[4];
  const float* W_in_t  = (const float*)d_in[5];
  const float* b_in_t  = (const float*)d_in[6];
  const float* W_out_t = (const float*)d_in[7];
  const float* b_out_t = (const float*)d_in[8];
  const float* alpha   = (const float*)d_in[9];
  float* out = (float*)d_out;

  u16* ws    = (u16*)d_ws;
  u16* wib   = ws;                    // 2304*768
  u16* wob   = wib + 1769472;         // 768*768
  u16* witb  = wob + 589824;
  u16* wotb  = witb + 1769472;
  u16* qkvb  = wotb + 589824;         // 25088*2304
  u16* reg1  = qkvb + 57802752;       // 25088*768
  u16* reg2  = reg1 + 19267584;       // 25088*768

  cvtk<<<dim3(1728),  256, 0, stream>>>(W_in,    wib,  442368);
  cvtk<<<dim3(576),   256, 0, stream>>>(W_out,   wob,  147456);
  cvtk<<<dim3(1728),  256, 0, stream>>>(W_in_t,  witb, 442368);
  cvtk<<<dim3(576),   256, 0, stream>>>(W_out_t, wotb, 147456);
  cvtk<<<dim3(18816), 256, 0, stream>>>(x,       reg1, 4816896);

  // qkv = x @ W_in^T + b_in            [25088 x 2304]   (8-phase, 256^2)
  gemm8<<<dim3(882), 512, 0, stream>>>(reg1, wib, b_in, qkvb, 2304, 9, 882);
  // spatial attention -> x2ab (bf16, reg1)
  attn_k<196, 0><<<dim3(128, 12), 256, 0, stream>>>(qkvb, nullptr, reg1);
  // x2 = x2ab @ W_out^T + b_out -> d_out (f32) + x2b (bf16, reg2)
  gemm_bt<1><<<dim3(1176), 256, 0, stream>>>(reg1, wob, b_out, nullptr,
                                             out, reg2, 768, 768, 6, 1176);
  // xt = x2b @ W_in_t^T + b_in_t       [25088 x 2304]   (8-phase, 256^2)
  gemm8<<<dim3(882), 512, 0, stream>>>(reg2, witb, b_in_t, qkvb, 2304, 9, 882);
  // th attention -> th_b (reg1); tw attention -> reg2 = tw + th
  attn_k<224, 1><<<dim3(112, 12), 256, 0, stream>>>(qkvb, nullptr, reg1);
  attn_k<224, 2><<<dim3(112, 12), 256, 0, stream>>>(qkvb, reg1, reg2);
  // d_out += ((th+tw) @ W_out_t^T + b_out_t) * alpha
  gemm_bt<2><<<dim3(1176), 256, 0, stream>>>(reg2, wotb, b_out_t, alpha,
                                             out, nullptr, 768, 768, 6, 1176);
}

// Round 5
// 600.963 us; speedup vs baseline: 1.1367x; 1.1367x over previous
//
#include <hip/hip_runtime.h>

typedef unsigned short u16;
typedef __attribute__((ext_vector_type(8))) short bf16x8;
typedef __attribute__((ext_vector_type(4))) float f32x4;

__device__ __forceinline__ u16 f2b(float f) {
  union { float f; unsigned u; } c; c.f = f;
  unsigned u = c.u + 0x7fffu + ((c.u >> 16) & 1u);
  return (u16)(u >> 16);
}
__device__ __forceinline__ float b2f(u16 h) {
  union { unsigned u; float f; } c; c.u = ((unsigned)h) << 16;
  return c.f;
}
__device__ __forceinline__ void g2lds16(const void* g, void* l) {
  __builtin_amdgcn_global_load_lds((const __attribute__((address_space(1))) void*)g,
                                   (__attribute__((address_space(3))) void*)l, 16, 0, 0);
}

// ---------------------------------------------------------------- f32 -> bf16 (x)
__global__ __launch_bounds__(256) void cvtk(const float* __restrict__ in,
                                            u16* __restrict__ out, int n4) {
  int i = blockIdx.x * 256 + threadIdx.x;
  if (i < n4) {
    float4 f = ((const float4*)in)[i];
    ushort4 o;
    o.x = f2b(f.x); o.y = f2b(f.y); o.z = f2b(f.z); o.w = f2b(f.w);
    ((ushort4*)out)[i] = o;
  }
}

// ---------------------------------------------------------------- all-weights convert
// segments (float4 chunks): [0,442368) W_in; [442368,589824) W_out;
// [589824,1032192) W_in_t; [1032192,1179648) W_out_t * alpha[row]
__global__ __launch_bounds__(256)
void cvtw(const float* __restrict__ W_in, const float* __restrict__ W_out,
          const float* __restrict__ W_in_t, const float* __restrict__ W_out_t,
          const float* __restrict__ alpha,
          u16* __restrict__ wib, u16* __restrict__ wob,
          u16* __restrict__ witb, u16* __restrict__ wotb) {
  int i = blockIdx.x * 256 + threadIdx.x;
  const float* src; u16* dst; int j; float sc = 1.f;
  if (i < 442368)        { src = W_in;    dst = wib;  j = i; }
  else if (i < 589824)   { src = W_out;   dst = wob;  j = i - 442368; }
  else if (i < 1032192)  { src = W_in_t;  dst = witb; j = i - 589824; }
  else if (i < 1179648)  { src = W_out_t; dst = wotb; j = i - 1032192; sc = alpha[j / 192]; }
  else return;
  float4 f = ((const float4*)src)[j];
  ushort4 o;
  o.x = f2b(f.x * sc); o.y = f2b(f.y * sc); o.z = f2b(f.z * sc); o.w = f2b(f.w * sc);
  ((ushort4*)dst)[j] = o;
}

// ---------------------------------------------------------------- bias prep
// bc[i] = sum_k W_in_t[i,k]*b_out[k] + b_in_t[i]   (i < 2304)
// bf[n] = b_out[n] + alpha[n]*b_out_t[n]           (n < 768)
__global__ __launch_bounds__(256)
void biask(const float* __restrict__ W_in_t, const float* __restrict__ b_out,
           const float* __restrict__ b_in_t, const float* __restrict__ b_out_t,
           const float* __restrict__ alpha, float* __restrict__ bc,
           float* __restrict__ bf) {
  int i = blockIdx.x * 256 + threadIdx.x;
  if (i < 2304) {
    float s = 0.f;
    for (int k = 0; k < 768; ++k) s += W_in_t[i * 768 + k] * b_out[k];
    bc[i] = s + b_in_t[i];
  } else if (i < 3072) {
    int n = i - 2304;
    bf[n] = b_out[n] + alpha[n] * b_out_t[n];
  }
}

// ---------------------------------------------------------------- GEMM (2-phase dbuf, proven)
// MODE 0: outb[m,n] = bf16( sum_k Aa[m,k]*Bw[n,k] + bias[n] )
// MODE 3: fused dual-source, K-loop 24 tiles: kt<12 uses (Aa,Bw), kt>=12 uses
//         (Aa2,Bw2); outf[m,n] = acc + bias[n]  (f32). All K=768 strides.
// 128x128 tile, BK=64, 4 waves; A,B via global_load_lds; dbuf + vmcnt(8).
// T2 swizzle: physical 16B part p of row r holds logical part p^(r&7).
// Grid 1D, m204 bijective XCD swizzle (any nwg).
template<int MODE>
__global__ __launch_bounds__(256)
void gemm_bt(const u16* __restrict__ Aa, const u16* __restrict__ Bw,
             const u16* __restrict__ Aa2, const u16* __restrict__ Bw2,
             const float* __restrict__ bias,
             float* __restrict__ outf, u16* __restrict__ outb,
             int N, int K, int NT, int nwg)
{
  __shared__ u16 As[2][128 * 64];
  __shared__ u16 Bs[2][128 * 64];
  const int tid = threadIdx.x;
  const int wave = tid >> 6, lane = tid & 63;
  const int r16 = lane & 15, rq = lane >> 4;
  const int wr = wave >> 1, wc = wave & 1;

  // m204 bijective XCD swizzle
  const int q8 = nwg >> 3, r8 = nwg & 7;
  const int xcd = blockIdx.x & 7, pos = blockIdx.x >> 3;
  const int wg = (xcd < r8 ? xcd * (q8 + 1) : r8 * (q8 + 1) + (xcd - r8) * q8) + pos;
  const long am0 = (long)(wg / NT) * 128;
  const long bn0 = (long)(wg % NT) * 128;

  f32x4 acc[4][4];
  const f32x4 zero = {0.f, 0.f, 0.f, 0.f};
#pragma unroll
  for (int i = 0; i < 4; ++i)
#pragma unroll
    for (int j = 0; j < 4; ++j) acc[i][j] = zero;

  const int split = K >> 6;                         // 12
  const int nkt = (MODE == 3) ? 2 * split : split;

  auto stage = [&](int kt, int buf) {
    const u16* Ap = Aa; const u16* Bp = Bw; int ko = kt;
    if constexpr (MODE == 3) {
      if (kt >= split) { Ap = Aa2; Bp = Bw2; ko = kt - split; }
    }
#pragma unroll
    for (int i = 0; i < 4; ++i) {
      int c = i * 256 + tid;
      int row = c >> 3;
      int lp = (c & 7) ^ (row & 7);
      g2lds16(Ap + (am0 + row) * (long)K + ko * 64 + lp * 8,
              As[buf] + (i * 256 + wave * 64) * 8);
      g2lds16(Bp + (bn0 + row) * (long)K + ko * 64 + lp * 8,
              Bs[buf] + (i * 256 + wave * 64) * 8);
    }
  };

  stage(0, 0);
  for (int kt = 0; kt < nkt; ++kt) {
    const int cur = kt & 1;
    if (kt + 1 < nkt) {
      stage(kt + 1, cur ^ 1);
      asm volatile("s_waitcnt vmcnt(8)" ::: "memory");   // tile kt landed; kt+1 in flight
    } else {
      asm volatile("s_waitcnt vmcnt(0)" ::: "memory");
    }
    __builtin_amdgcn_sched_barrier(0);
    __builtin_amdgcn_s_barrier();
    __builtin_amdgcn_sched_barrier(0);
#pragma unroll
    for (int kk = 0; kk < 2; ++kk) {
      bf16x8 af[4], bfr[4];
#pragma unroll
      for (int i = 0; i < 4; ++i) {
        int ra = wr * 64 + i * 16 + r16;
        af[i] = *(const bf16x8*)(As[cur] + ((ra * 128 + ((kk * 64 + rq * 16) ^ ((ra & 7) << 4))) >> 1));
        int rb = wc * 64 + i * 16 + r16;
        bfr[i] = *(const bf16x8*)(Bs[cur] + ((rb * 128 + ((kk * 64 + rq * 16) ^ ((rb & 7) << 4))) >> 1));
      }
#pragma unroll
      for (int i = 0; i < 4; ++i)
#pragma unroll
        for (int j = 0; j < 4; ++j)
          acc[i][j] = __builtin_amdgcn_mfma_f32_16x16x32_bf16(af[i], bfr[j], acc[i][j], 0, 0, 0);
    }
    __builtin_amdgcn_sched_barrier(0);
    __builtin_amdgcn_s_barrier();
    __builtin_amdgcn_sched_barrier(0);
  }

  // epilogue: D row=(lane>>4)*4+r, col=lane&15
#pragma unroll
  for (int j = 0; j < 4; ++j) {
    int col = (int)bn0 + wc * 64 + j * 16 + r16;
    float bb = bias ? bias[col] : 0.f;
#pragma unroll
    for (int i = 0; i < 4; ++i) {
      long row = am0 + wr * 64 + i * 16 + rq * 4;
#pragma unroll
      for (int r = 0; r < 4; ++r) {
        float v = acc[i][j][r] + bb;
        long idx = (row + r) * (long)N + col;
        if constexpr (MODE == 0) outb[idx] = f2b(v);
        else                     outf[idx] = v;
      }
    }
  }
}

// ---------------------------------------------------------------- attention
// One workgroup per (group g, head h). qkv rows indexed via mode mapping:
//   MODE 0 (spatial): row = g*196 + s
//   MODE 1 (th): g=(b,w): row = b*3136 + w + (s/14)*196 + (s%14)*14
//   MODE 2 (tw): g=(b,h'): row = b*3136 + h'*14 + (s/14)*196 + (s%14)
// Output bf16; MODE 2 adds addin[idx] (th result; may alias outp — each idx
// is read once then written once by the same thread).
template<int S, int MODE>
__global__ __launch_bounds__(256)
void attn_k(const u16* __restrict__ qkv, const u16* __restrict__ addin,
            u16* __restrict__ outp)
{
  constexpr int NT = (S + 15) / 16;   // 13 (S=196) or 14 (S=224)
  constexpr int NB = (NT + 1) / 2;    // 7
  __shared__ u16 Ks[224 * 64];
  __shared__ u16 Vt[64 * 224];
  __shared__ u16 Ps[4][512];

  const int g = blockIdx.x, h = blockIdx.y;
  const int tid = threadIdx.x;
  const int wave = tid >> 6, lane = tid & 63;
  const int r16 = lane & 15, rq = lane >> 4;

  int base;
  if constexpr (MODE == 0) base = g * 196;
  else if constexpr (MODE == 1) base = (g / 14) * 3136 + (g % 14);
  else base = (g / 14) * 3136 + (g % 14) * 14;

  auto rowof = [&](int s) -> long {
    if constexpr (MODE == 0) return base + s;
    int t = s / 14, u = s % 14;
    return base + t * 196 + u * (MODE == 1 ? 14 : 1);
  };

#pragma unroll
  for (int i = 0; i < 7; ++i) {
    int c = i * 256 + tid;
    int s = c >> 3, part = c & 7;
    int sc = (s < S) ? s : (S - 1);
    g2lds16(qkv + rowof(sc) * 2304 + 768 + h * 64 + ((part ^ (s & 7)) << 3),
            &Ks[(i * 256 + wave * 64) * 8]);
  }
#pragma unroll
  for (int i = 0; i < 7; ++i) {
    int c = i * 256 + tid;
    int s = c >> 3, part = c & 7;
    uint4 v; v.x = 0; v.y = 0; v.z = 0; v.w = 0;
    if (s < S) v = *(const uint4*)(qkv + rowof(s) * 2304 + 1536 + h * 64 + part * 8);
#pragma unroll
    for (int e = 0; e < 4; ++e) {
      unsigned w2 = (&v.x)[e];
      Vt[(part * 8 + 2 * e    ) * 224 + s] = (u16)(w2 & 0xffffu);
      Vt[(part * 8 + 2 * e + 1) * 224 + s] = (u16)(w2 >> 16);
    }
  }
  __syncthreads();

  for (int qt = wave; qt < NT; qt += 4) {
    int q0 = qt * 16;
    int qr = q0 + r16; if (qr > S - 1) qr = S - 1;
    const u16* gq = qkv + rowof(qr) * 2304 + h * 64 + rq * 8;
    bf16x8 aq0 = *(const bf16x8*)(gq);
    bf16x8 aq1 = *(const bf16x8*)(gq + 32);

    float p[4][NT];
#pragma unroll
    for (int kt = 0; kt < NT; ++kt) {
      f32x4 sc4 = {0.f, 0.f, 0.f, 0.f};
      int row = kt * 16 + r16;
      sc4 = __builtin_amdgcn_mfma_f32_16x16x32_bf16(
          aq0, *(const bf16x8*)(Ks + ((row * 128 + ((rq * 16) ^ ((row & 7) << 4))) >> 1)), sc4, 0, 0, 0);
      sc4 = __builtin_amdgcn_mfma_f32_16x16x32_bf16(
          aq1, *(const bf16x8*)(Ks + ((row * 128 + ((64 + rq * 16) ^ ((row & 7) << 4))) >> 1)), sc4, 0, 0, 0);
#pragma unroll
      for (int r = 0; r < 4; ++r) {
        float sv = sc4[r] * 0.125f;
        if (S == 196 && kt == NT - 1) {
          if (kt * 16 + r16 >= S) sv = -1e30f;
        }
        p[r][kt] = sv;
      }
    }

    float rcp[4];
#pragma unroll
    for (int r = 0; r < 4; ++r) {
      float m = p[r][0];
#pragma unroll
      for (int kt = 1; kt < NT; ++kt) m = fmaxf(m, p[r][kt]);
      m = fmaxf(m, __shfl_xor(m, 1));
      m = fmaxf(m, __shfl_xor(m, 2));
      m = fmaxf(m, __shfl_xor(m, 4));
      m = fmaxf(m, __shfl_xor(m, 8));
      float sum = 0.f;
#pragma unroll
      for (int kt = 0; kt < NT; ++kt) {
        float e = __expf(p[r][kt] - m);
        p[r][kt] = e; sum += e;
      }
      sum += __shfl_xor(sum, 1);
      sum += __shfl_xor(sum, 2);
      sum += __shfl_xor(sum, 4);
      sum += __shfl_xor(sum, 8);
      rcp[r] = 1.f / sum;
    }

    f32x4 oacc[4];
    const f32x4 zero = {0.f, 0.f, 0.f, 0.f};
#pragma unroll
    for (int nt = 0; nt < 4; ++nt) oacc[nt] = zero;
    u16* myP = Ps[wave];
#pragma unroll
    for (int jb = 0; jb < NB; ++jb) {
#pragma unroll
      for (int half = 0; half < 2; ++half) {
        int kt = jb * 2 + half;
#pragma unroll
        for (int r = 0; r < 4; ++r) {
          float pv = (kt < NT) ? p[r][kt] : 0.f;
          myP[(rq * 4 + r) * 32 + half * 16 + r16] = f2b(pv);
        }
      }
      asm volatile("s_waitcnt lgkmcnt(0)" ::: "memory");
      __builtin_amdgcn_sched_barrier(0);
      bf16x8 ap = *(const bf16x8*)(myP + r16 * 32 + rq * 8);
#pragma unroll
      for (int nt = 0; nt < 4; ++nt) {
        bf16x8 bv = *(const bf16x8*)(Vt + (nt * 16 + r16) * 224 + jb * 32 + rq * 8);
        oacc[nt] = __builtin_amdgcn_mfma_f32_16x16x32_bf16(ap, bv, oacc[nt], 0, 0, 0);
      }
      asm volatile("s_waitcnt lgkmcnt(0)" ::: "memory");
      __builtin_amdgcn_sched_barrier(0);
    }

#pragma unroll
    for (int r = 0; r < 4; ++r) {
      int q = q0 + rq * 4 + r;
      if (q < S) {
        long orow = rowof(q);
#pragma unroll
        for (int nt = 0; nt < 4; ++nt) {
          float v = oacc[nt][r] * rcp[r];
          long idx = orow * 768 + h * 64 + nt * 16 + r16;
          if constexpr (MODE == 2) v += b2f(addin[idx]);
          outp[idx] = f2b(v);
        }
      }
    }
  }
}

// ---------------------------------------------------------------- launch
extern "C" void kernel_launch(void* const* d_in, const int* in_sizes, int n_in,
                              void* d_out, int out_size, void* d_ws, size_t ws_size,
                              hipStream_t stream)
{
  const float* x       = (const float*)d_in[0];
  const float* W_in    = (const float*)d_in[1];
  const float* b_in    = (const float*)d_in[2];
  const float* W_out   = (const float*)d_in[3];
  const float* b_out   = (const float*)d_in[4];
  const float* W_in_t  = (const float*)d_in[5];
  const float* b_in_t  = (const float*)d_in[6];
  const float* W_out_t = (const float*)d_in[7];
  const float* b_out_t = (const float*)d_in[8];
  const float* alpha   = (const float*)d_in[9];
  float* out = (float*)d_out;

  // workspace (u16 units; 202,113,024 bytes total, same as proven footprint):
  //  wib (later bc/bf f32 overlay) | wob | wotb(alpha-scaled) | wcb |
  //  qkvb (witb overlays its head pre-qkv) | reg1 (xb -> a2) | reg2 (th -> th+tw)
  u16* ws    = (u16*)d_ws;
  u16* wib   = ws;                    // 2304*768
  u16* wob   = wib + 1769472;         // 768*768
  u16* wotb  = wob + 589824;          // 768*768 (pre-scaled by alpha[row])
  u16* wcb   = wotb + 589824;         // 2304*768  Wc = W_in_t @ W_out
  u16* qkvb  = wcb + 1769472;         // 25088*2304
  u16* witb  = qkvb;                  // temp overlay (dead after wc gemm)
  u16* reg1  = qkvb + 57802752;       // 25088*768
  u16* reg2  = reg1 + 19267584;       // 25088*768
  float* bc  = (float*)wib;           // 2304 f32 (overlay after qkv gemm)
  float* bf  = bc + 2304;             // 768 f32

  // weight + x conversions
  cvtw<<<dim3(4608), 256, 0, stream>>>(W_in, W_out, W_in_t, W_out_t, alpha,
                                       wib, wob, witb, wotb);
  cvtk<<<dim3(18816), 256, 0, stream>>>(x, reg1, 4816896);

  // Wc = W_in_t @ W_out^T-form: Wc[i,j] = sum_k witb[i,k]*wob[j,k]  [2304 x 768]
  gemm_bt<0><<<dim3(108), 256, 0, stream>>>(witb, wob, nullptr, nullptr, nullptr,
                                            nullptr, wcb, 768, 768, 6, 108);
  // qkv = x @ W_in^T + b_in            [25088 x 2304]
  gemm_bt<0><<<dim3(3528), 256, 0, stream>>>(reg1, wib, nullptr, nullptr, b_in,
                                             nullptr, qkvb, 2304, 768, 18, 3528);
  // bias folds (wib now dead -> bc/bf overlay)
  biask<<<dim3(12), 256, 0, stream>>>(W_in_t, b_out, b_in_t, b_out_t, alpha, bc, bf);
  // spatial attention -> a2 (bf16, reg1; xb dead)
  attn_k<196, 0><<<dim3(128, 12), 256, 0, stream>>>(qkvb, nullptr, reg1);
  // xt = a2 @ Wc^T + bc                [25088 x 2304] (reuse qkvb)
  gemm_bt<0><<<dim3(3528), 256, 0, stream>>>(reg1, wcb, nullptr, nullptr, bc,
                                             nullptr, qkvb, 2304, 768, 18, 3528);
  // th attention -> reg2; tw attention -> reg2 = tw + th (in place)
  attn_k<224, 1><<<dim3(112, 12), 256, 0, stream>>>(qkvb, nullptr, reg2);
  attn_k<224, 2><<<dim3(112, 12), 256, 0, stream>>>(qkvb, reg2, reg2);
  // out = a2 @ W_out^T + (th+tw) @ (alpha*W_out_t)^T + bf   (fused, f32)
  gemm_bt<3><<<dim3(1176), 256, 0, stream>>>(reg1, wob, reg2, wotb, bf,
                                             out, nullptr, 768, 768, 6, 1176);
}

// Round 6
// 584.342 us; speedup vs baseline: 1.1690x; 1.0284x over previous
//
#include <hip/hip_runtime.h>

typedef unsigned short u16;
typedef __attribute__((ext_vector_type(8))) short bf16x8;
typedef __attribute__((ext_vector_type(4))) float f32x4;

__device__ __forceinline__ u16 f2b(float f) {
  union { float f; unsigned u; } c; c.f = f;
  unsigned u = c.u + 0x7fffu + ((c.u >> 16) & 1u);
  return (u16)(u >> 16);
}
__device__ __forceinline__ float b2f(u16 h) {
  union { unsigned u; float f; } c; c.u = ((unsigned)h) << 16;
  return c.f;
}
__device__ __forceinline__ void g2lds16(const void* g, void* l) {
  __builtin_amdgcn_global_load_lds((const __attribute__((address_space(1))) void*)g,
                                   (__attribute__((address_space(3))) void*)l, 16, 0, 0);
}

// ---------------------------------------------------------------- f32 -> bf16 (x)
__global__ __launch_bounds__(256) void cvtk(const float* __restrict__ in,
                                            u16* __restrict__ out, int n4) {
  int i = blockIdx.x * 256 + threadIdx.x;
  if (i < n4) {
    float4 f = ((const float4*)in)[i];
    ushort4 o;
    o.x = f2b(f.x); o.y = f2b(f.y); o.z = f2b(f.z); o.w = f2b(f.w);
    ((ushort4*)out)[i] = o;
  }
}

// ---------------------------------------------------------------- all-weights convert
__global__ __launch_bounds__(256)
void cvtw(const float* __restrict__ W_in, const float* __restrict__ W_out,
          const float* __restrict__ W_in_t, const float* __restrict__ W_out_t,
          const float* __restrict__ alpha,
          u16* __restrict__ wib, u16* __restrict__ wob,
          u16* __restrict__ witb, u16* __restrict__ wotb) {
  int i = blockIdx.x * 256 + threadIdx.x;
  const float* src; u16* dst; int j; float sc = 1.f;
  if (i < 442368)        { src = W_in;    dst = wib;  j = i; }
  else if (i < 589824)   { src = W_out;   dst = wob;  j = i - 442368; }
  else if (i < 1032192)  { src = W_in_t;  dst = witb; j = i - 589824; }
  else if (i < 1179648)  { src = W_out_t; dst = wotb; j = i - 1032192; sc = alpha[j / 192]; }
  else return;
  float4 f = ((const float4*)src)[j];
  ushort4 o;
  o.x = f2b(f.x * sc); o.y = f2b(f.y * sc); o.z = f2b(f.z * sc); o.w = f2b(f.w * sc);
  ((ushort4*)dst)[j] = o;
}

// ---------------------------------------------------------------- bias prep
__global__ __launch_bounds__(256)
void biask(const float* __restrict__ W_in_t, const float* __restrict__ b_out,
           const float* __restrict__ b_in_t, const float* __restrict__ b_out_t,
           const float* __restrict__ alpha, float* __restrict__ bc,
           float* __restrict__ bf) {
  int i = blockIdx.x * 256 + threadIdx.x;
  if (i < 2304) {
    float s = 0.f;
    for (int k = 0; k < 768; ++k) s += W_in_t[i * 768 + k] * b_out[k];
    bc[i] = s + b_in_t[i];
  } else if (i < 3072) {
    int n = i - 2304;
    bf[n] = b_out[n] + alpha[n] * b_out_t[n];
  }
}

// ---------------------------------------------------------------- GEMM (2-phase dbuf, proven)
// MODE 0: outb[m,n] = bf16( sum_k Aa[m,k]*Bw[n,k] + bias[n] )
// MODE 3: fused dual-source, 24 k-tiles: kt<12 (Aa,Bw), kt>=12 (Aa2,Bw2);
//         outf = acc + bias (f32).
template<int MODE>
__global__ __launch_bounds__(256)
void gemm_bt(const u16* __restrict__ Aa, const u16* __restrict__ Bw,
             const u16* __restrict__ Aa2, const u16* __restrict__ Bw2,
             const float* __restrict__ bias,
             float* __restrict__ outf, u16* __restrict__ outb,
             int N, int K, int NT, int nwg)
{
  __shared__ u16 As[2][128 * 64];
  __shared__ u16 Bs[2][128 * 64];
  const int tid = threadIdx.x;
  const int wave = tid >> 6, lane = tid & 63;
  const int r16 = lane & 15, rq = lane >> 4;
  const int wr = wave >> 1, wc = wave & 1;

  const int q8 = nwg >> 3, r8 = nwg & 7;
  const int xcd = blockIdx.x & 7, pos = blockIdx.x >> 3;
  const int wg = (xcd < r8 ? xcd * (q8 + 1) : r8 * (q8 + 1) + (xcd - r8) * q8) + pos;
  const long am0 = (long)(wg / NT) * 128;
  const long bn0 = (long)(wg % NT) * 128;

  f32x4 acc[4][4];
  const f32x4 zero = {0.f, 0.f, 0.f, 0.f};
#pragma unroll
  for (int i = 0; i < 4; ++i)
#pragma unroll
    for (int j = 0; j < 4; ++j) acc[i][j] = zero;

  const int split = K >> 6;
  const int nkt = (MODE == 3) ? 2 * split : split;

  auto stage = [&](int kt, int buf) {
    const u16* Ap = Aa; const u16* Bp = Bw; int ko = kt;
    if constexpr (MODE == 3) {
      if (kt >= split) { Ap = Aa2; Bp = Bw2; ko = kt - split; }
    }
#pragma unroll
    for (int i = 0; i < 4; ++i) {
      int c = i * 256 + tid;
      int row = c >> 3;
      int lp = (c & 7) ^ (row & 7);
      g2lds16(Ap + (am0 + row) * (long)K + ko * 64 + lp * 8,
              As[buf] + (i * 256 + wave * 64) * 8);
      g2lds16(Bp + (bn0 + row) * (long)K + ko * 64 + lp * 8,
              Bs[buf] + (i * 256 + wave * 64) * 8);
    }
  };

  stage(0, 0);
  for (int kt = 0; kt < nkt; ++kt) {
    const int cur = kt & 1;
    if (kt + 1 < nkt) {
      stage(kt + 1, cur ^ 1);
      asm volatile("s_waitcnt vmcnt(8)" ::: "memory");
    } else {
      asm volatile("s_waitcnt vmcnt(0)" ::: "memory");
    }
    __builtin_amdgcn_sched_barrier(0);
    __builtin_amdgcn_s_barrier();
    __builtin_amdgcn_sched_barrier(0);
#pragma unroll
    for (int kk = 0; kk < 2; ++kk) {
      bf16x8 af[4], bfr[4];
#pragma unroll
      for (int i = 0; i < 4; ++i) {
        int ra = wr * 64 + i * 16 + r16;
        af[i] = *(const bf16x8*)(As[cur] + ((ra * 128 + ((kk * 64 + rq * 16) ^ ((ra & 7) << 4))) >> 1));
        int rb = wc * 64 + i * 16 + r16;
        bfr[i] = *(const bf16x8*)(Bs[cur] + ((rb * 128 + ((kk * 64 + rq * 16) ^ ((rb & 7) << 4))) >> 1));
      }
#pragma unroll
      for (int i = 0; i < 4; ++i)
#pragma unroll
        for (int j = 0; j < 4; ++j)
          acc[i][j] = __builtin_amdgcn_mfma_f32_16x16x32_bf16(af[i], bfr[j], acc[i][j], 0, 0, 0);
    }
    __builtin_amdgcn_sched_barrier(0);
    __builtin_amdgcn_s_barrier();
    __builtin_amdgcn_sched_barrier(0);
  }

#pragma unroll
  for (int j = 0; j < 4; ++j) {
    int col = (int)bn0 + wc * 64 + j * 16 + r16;
    float bb = bias ? bias[col] : 0.f;
#pragma unroll
    for (int i = 0; i < 4; ++i) {
      long row = am0 + wr * 64 + i * 16 + rq * 4;
#pragma unroll
      for (int r = 0; r < 4; ++r) {
        float v = acc[i][j][r] + bb;
        long idx = (row + r) * (long)N + col;
        if constexpr (MODE == 0) outb[idx] = f2b(v);
        else                     outf[idx] = v;
      }
    }
  }
}

// ---------------------------------------------------------------- attention
// One workgroup per (group g, head h). qkv rows via mode mapping:
//   MODE 0 (spatial): row = g*196 + s
//   MODE 1 (th): g=(b,w): row = b*3136 + w + (s/14)*196 + (s%14)*14
//   MODE 2 (tw): g=(b,h'): row = b*3136 + h'*14 + (s/14)*196 + (s%14)
// Output bf16; MODE 2 adds addin[idx] (may alias outp; idx read-then-write
// by the same thread).
// Vt layout (conflict-free, gemm-proven XOR pattern): 128-B rows,
//   u16 idx(d,s) = (s>>6)*4096 + d*64 + ((s&63) ^ ((d&7)<<3)).
// V staging is s-major per wave (64 consecutive s, part fixed) so each
// ds_write_b16 spreads 32 banks x 2 lanes (free). Pad rows s>=S are clamped
// copies; P=0 there so contribution is exactly 0.
template<int S, int MODE>
__global__ __launch_bounds__(256)
void attn_k(const u16* __restrict__ qkv, const u16* __restrict__ addin,
            u16* __restrict__ outp)
{
  constexpr int NT = (S + 15) / 16;   // 13 (S=196) or 14 (S=224)
  constexpr int NB = (NT + 1) / 2;    // 7
  __shared__ u16 Ks[224 * 64];        // K rows, 128-B rows, XOR-swizzled
  __shared__ u16 Vt[16384];           // V^T, 4 s-blocks x 64 d-rows x 64
  __shared__ u16 Ps[4][512];          // per-wave P scratch [16][32]

  const int g = blockIdx.x, h = blockIdx.y;
  const int tid = threadIdx.x;
  const int wave = tid >> 6, lane = tid & 63;
  const int r16 = lane & 15, rq = lane >> 4;

  int base;
  if constexpr (MODE == 0) base = g * 196;
  else if constexpr (MODE == 1) base = (g / 14) * 3136 + (g % 14);
  else base = (g / 14) * 3136 + (g % 14) * 14;

  auto rowof = [&](int s) -> long {
    if constexpr (MODE == 0) return base + s;
    int t = s / 14, u = s % 14;
    return base + t * 196 + u * (MODE == 1 ? 14 : 1);
  };

  // ---- stage K (row-major 128-B rows, swizzled) via global_load_lds ----
#pragma unroll
  for (int i = 0; i < 7; ++i) {
    int c = i * 256 + tid;            // 224 rows x 8 parts
    int s = c >> 3, part = c & 7;
    int sc = (s < S) ? s : (S - 1);
    g2lds16(qkv + rowof(sc) * 2304 + 768 + h * 64 + ((part ^ (s & 7)) << 3),
            &Ks[(i * 256 + wave * 64) * 8]);
  }
  // ---- stage V transposed, s-major lanes, conflict-free writes ----
#pragma unroll
  for (int i = 0; i < 7; ++i) {
    int c = i * 256 + tid;
    int sb, part, slo;
    if (c < 1536) { sb = c >> 9; part = (c >> 6) & 7; slo = c & 63; }
    else { int c2 = c - 1536; sb = 3; part = c2 >> 5; slo = c2 & 31; }
    int s = sb * 64 + slo;
    int sc = (s < S) ? s : (S - 1);
    uint4 v = *(const uint4*)(qkv + rowof(sc) * 2304 + 1536 + h * 64 + part * 8);
    u16* vb = Vt + sb * 4096;
#pragma unroll
    for (int e = 0; e < 4; ++e) {
      unsigned w2 = (&v.x)[e];
      int d0 = part * 8 + 2 * e;                    // d0&7 = 2e
      vb[d0 * 64 + (slo ^ ((2 * e) << 3))]       = (u16)(w2 & 0xffffu);
      vb[(d0 + 1) * 64 + (slo ^ ((2 * e + 1) << 3))] = (u16)(w2 >> 16);
    }
  }
  __syncthreads();

  // ---- per-wave q-tiles (16 rows each) ----
  for (int qt = wave; qt < NT; qt += 4) {
    int q0 = qt * 16;
    int qr = q0 + r16; if (qr > S - 1) qr = S - 1;
    const u16* gq = qkv + rowof(qr) * 2304 + h * 64 + rq * 8;
    bf16x8 aq0 = *(const bf16x8*)(gq);
    bf16x8 aq1 = *(const bf16x8*)(gq + 32);

    float p[4][NT];
#pragma unroll
    for (int kt = 0; kt < NT; ++kt) {
      f32x4 sc4 = {0.f, 0.f, 0.f, 0.f};
      int row = kt * 16 + r16;
      sc4 = __builtin_amdgcn_mfma_f32_16x16x32_bf16(
          aq0, *(const bf16x8*)(Ks + ((row * 128 + ((rq * 16) ^ ((row & 7) << 4))) >> 1)), sc4, 0, 0, 0);
      sc4 = __builtin_amdgcn_mfma_f32_16x16x32_bf16(
          aq1, *(const bf16x8*)(Ks + ((row * 128 + ((64 + rq * 16) ^ ((row & 7) << 4))) >> 1)), sc4, 0, 0, 0);
#pragma unroll
      for (int r = 0; r < 4; ++r) {
        float sv = sc4[r] * 0.125f;
        if (S == 196 && kt == NT - 1) {
          if (kt * 16 + r16 >= S) sv = -1e30f;   // mask padded keys
        }
        p[r][kt] = sv;
      }
    }

    // ---- softmax (rows live in 16-lane groups sharing rq) ----
    float rcp[4];
#pragma unroll
    for (int r = 0; r < 4; ++r) {
      float m = p[r][0];
#pragma unroll
      for (int kt = 1; kt < NT; ++kt) m = fmaxf(m, p[r][kt]);
      m = fmaxf(m, __shfl_xor(m, 1));
      m = fmaxf(m, __shfl_xor(m, 2));
      m = fmaxf(m, __shfl_xor(m, 4));
      m = fmaxf(m, __shfl_xor(m, 8));
      float sum = 0.f;
#pragma unroll
      for (int kt = 0; kt < NT; ++kt) {
        float e = __expf(p[r][kt] - m);
        p[r][kt] = e; sum += e;
      }
      sum += __shfl_xor(sum, 1);
      sum += __shfl_xor(sum, 2);
      sum += __shfl_xor(sum, 4);
      sum += __shfl_xor(sum, 8);
      rcp[r] = 1.f / sum;
    }

    // ---- PV via per-wave LDS round-trip of P ----
    f32x4 oacc[4];
    const f32x4 zero = {0.f, 0.f, 0.f, 0.f};
#pragma unroll
    for (int nt = 0; nt < 4; ++nt) oacc[nt] = zero;
    u16* myP = Ps[wave];
#pragma unroll
    for (int jb = 0; jb < NB; ++jb) {
#pragma unroll
      for (int half = 0; half < 2; ++half) {
        int kt = jb * 2 + half;
#pragma unroll
        for (int r = 0; r < 4; ++r) {
          float pv = (kt < NT) ? p[r][kt] : 0.f;
          myP[(rq * 4 + r) * 32 + half * 16 + r16] = f2b(pv);
        }
      }
      asm volatile("s_waitcnt lgkmcnt(0)" ::: "memory");  // cross-lane: writes visible
      __builtin_amdgcn_sched_barrier(0);
      bf16x8 ap = *(const bf16x8*)(myP + r16 * 32 + rq * 8);
#pragma unroll
      for (int nt = 0; nt < 4; ++nt) {
        bf16x8 bv = *(const bf16x8*)(Vt + (jb >> 1) * 4096 + (nt * 16 + r16) * 64 +
                                     (((jb & 1) * 32 + rq * 8) ^ ((r16 & 7) << 3)));
        oacc[nt] = __builtin_amdgcn_mfma_f32_16x16x32_bf16(ap, bv, oacc[nt], 0, 0, 0);
      }
      asm volatile("s_waitcnt lgkmcnt(0)" ::: "memory");  // reads done before overwrite
      __builtin_amdgcn_sched_barrier(0);
    }

    // ---- write out (bf16); MODE 2 adds th result ----
#pragma unroll
    for (int r = 0; r < 4; ++r) {
      int q = q0 + rq * 4 + r;
      if (q < S) {
        long orow = rowof(q);
#pragma unroll
        for (int nt = 0; nt < 4; ++nt) {
          float v = oacc[nt][r] * rcp[r];
          long idx = orow * 768 + h * 64 + nt * 16 + r16;
          if constexpr (MODE == 2) v += b2f(addin[idx]);
          outp[idx] = f2b(v);
        }
      }
    }
  }
}

// ---------------------------------------------------------------- launch
extern "C" void kernel_launch(void* const* d_in, const int* in_sizes, int n_in,
                              void* d_out, int out_size, void* d_ws, size_t ws_size,
                              hipStream_t stream)
{
  const float* x       = (const float*)d_in[0];
  const float* W_in    = (const float*)d_in[1];
  const float* b_in    = (const float*)d_in[2];
  const float* W_out   = (const float*)d_in[3];
  const float* b_out   = (const float*)d_in[4];
  const float* W_in_t  = (const float*)d_in[5];
  const float* b_in_t  = (const float*)d_in[6];
  const float* W_out_t = (const float*)d_in[7];
  const float* b_out_t = (const float*)d_in[8];
  const float* alpha   = (const float*)d_in[9];
  float* out = (float*)d_out;

  u16* ws    = (u16*)d_ws;
  u16* wib   = ws;                    // 2304*768
  u16* wob   = wib + 1769472;         // 768*768
  u16* wotb  = wob + 589824;          // 768*768 (alpha-scaled)
  u16* wcb   = wotb + 589824;         // 2304*768  Wc = W_in_t @ W_out
  u16* qkvb  = wcb + 1769472;         // 25088*2304
  u16* witb  = qkvb;                  // temp overlay (dead after wc gemm)
  u16* reg1  = qkvb + 57802752;       // 25088*768
  u16* reg2  = reg1 + 19267584;       // 25088*768
  float* bc  = (float*)wib;           // 2304 f32 (overlay after qkv gemm)
  float* bf  = bc + 2304;             // 768 f32

  cvtw<<<dim3(4608), 256, 0, stream>>>(W_in, W_out, W_in_t, W_out_t, alpha,
                                       wib, wob, witb, wotb);
  cvtk<<<dim3(18816), 256, 0, stream>>>(x, reg1, 4816896);

  // Wc[i,j] = sum_k witb[i,k]*wob[j,k]  [2304 x 768]
  gemm_bt<0><<<dim3(108), 256, 0, stream>>>(witb, wob, nullptr, nullptr, nullptr,
                                            nullptr, wcb, 768, 768, 6, 108);
  // qkv = x @ W_in^T + b_in            [25088 x 2304]
  gemm_bt<0><<<dim3(3528), 256, 0, stream>>>(reg1, wib, nullptr, nullptr, b_in,
                                             nullptr, qkvb, 2304, 768, 18, 3528);
  biask<<<dim3(12), 256, 0, stream>>>(W_in_t, b_out, b_in_t, b_out_t, alpha, bc, bf);
  // spatial attention -> a2 (bf16, reg1)
  attn_k<196, 0><<<dim3(128, 12), 256, 0, stream>>>(qkvb, nullptr, reg1);
  // xt = a2 @ Wc^T + bc                [25088 x 2304]
  gemm_bt<0><<<dim3(3528), 256, 0, stream>>>(reg1, wcb, nullptr, nullptr, bc,
                                             nullptr, qkvb, 2304, 768, 18, 3528);
  // th attention -> reg2; tw attention -> reg2 = tw + th (in place)
  attn_k<224, 1><<<dim3(112, 12), 256, 0, stream>>>(qkvb, nullptr, reg2);
  attn_k<224, 2><<<dim3(112, 12), 256, 0, stream>>>(qkvb, reg2, reg2);
  // out = a2 @ W_out^T + (th+tw) @ (alpha*W_out_t)^T + bf
  gemm_bt<3><<<dim3(1176), 256, 0, stream>>>(reg1, wob, reg2, wotb, bf,
                                             out, nullptr, 768, 768, 6, 1176);
}